// Round 10
// baseline (274.704 us; speedup 1.0000x reference)
//
#include <hip/hip_runtime.h>
#include <hip/hip_cooperative_groups.h>
namespace cg = cooperative_groups;

#define BB 4
#define CCH 384
#define HH 56
#define WWD 56
#define HW 3136
#define S2 49
#define S2P 52
#define D2 192
#define K2 25
#define XSP 20          // attn xs leading dim
#define NBS 196         // BB*S2

// One cooperative kernel, 4 stages separated by grid.sync():
//   1: GTt GEMM (vb<576) + ctx pool->PT (vb 576..911)
//   2: M = GTt . PT            (blocks 0..191)
//   3: attn 16px tiles (784)   (R7-verified body)
//   4: 5x5 dynamic stencil (672 tiles)
// LDS: 45KB union (stage-4 xt[16][12][60] is max). 256 thr/block.
__global__ __launch_bounds__(256, 2) void mega_k(
    const float* __restrict__ x, const float* __restrict__ ctx,
    const float* __restrict__ Wq, const float* __restrict__ Wk,
    const float* __restrict__ Wwd, float* __restrict__ GT,
    float* __restrict__ PT, float* __restrict__ M,
    float* __restrict__ dyn, float* __restrict__ out)
{
    cg::grid_group grid = cg::this_grid();
    __shared__ float sh[11520];          // 46080 B
    const int bid = blockIdx.x, t = threadIdx.x, G = gridDim.x;

    // ================= stage 1: GTt GEMM + pool =================
    for (int vb = bid; vb < 912; vb += G) {
        if (vb < 576) {
            float* As = sh; float* Bs = sh + 3072;
            int bi = vb % 24, bj = vb / 24;
            int tj = t & 15, ti = t >> 4;
#pragma unroll
            for (int k = 0; k < 3; k++) {
                int idx = t + 256 * k;
                int d = idx >> 2, q = idx & 3;
                *(float4*)&As[idx * 4] = *(const float4*)&Wq[(size_t)d * CCH + bi * 16 + 4 * q];
                *(float4*)&Bs[idx * 4] = *(const float4*)&Wk[(size_t)d * CCH + bj * 16 + 4 * q];
            }
            __syncthreads();
            float acc = 0.f;
#pragma unroll 8
            for (int d = 0; d < D2; d++)
                acc += As[d * 16 + ti] * Bs[d * 16 + tj];
            GT[(size_t)(bi * 16 + ti) * CCH + bj * 16 + tj] = acc;
        } else {
            float* part = sh;            // [32][8][14]
            int pb = vb - 576;           // b*84 + sy*12 + cgrp
            int b  = pb / 84;
            int rem = pb - b * 84;
            int sy = rem / 12;
            int cgrp = rem - sy * 12;
            int c0 = cgrp * 32;
            const float* base = ctx + ((size_t)(b * CCH + c0)) * HW + sy * 8 * WWD;
#pragma unroll
            for (int k = 0; k < 14; k++) {
                int g = t + 256 * k;     // [0, 3584)
                int cc = g / 112;
                int r2 = g - cc * 112;
                float4 v = *(const float4*)(base + (size_t)cc * HW + 4 * r2);
                part[g] = (v.x + v.y) + (v.z + v.w);
            }
            __syncthreads();
            if (t < 224) {
                int cc = t / 7, sx = t - cc * 7;
                float sum = 0.f;
#pragma unroll
                for (int r = 0; r < 8; r++)
                    sum += part[cc * 112 + r * 14 + 2 * sx]
                         + part[cc * 112 + r * 14 + 2 * sx + 1];
                int bs = b * S2 + sy * 7 + sx;
                PT[(size_t)(c0 + cc) * NBS + bs] = sum * (1.f / 64.f);
            }
        }
        __syncthreads();
    }
    grid.sync();

    // ================= stage 2: M = GTt . PT =================
    if (bid < 192) {
        int r = bid * 2 + (t >> 7);
        int c = t & 127;
        bool has1 = (c < NBS - 128);
        int c1 = has1 ? c + 128 : c;
        const float* g = GT + (size_t)r * CCH;
        float a0 = 0.f, a1 = 0.f;
#pragma unroll 8
        for (int i = 0; i < CCH; i++) {
            float gv = g[i];
            a0 += gv * PT[(size_t)i * NBS + c];
            a1 += gv * PT[(size_t)i * NBS + c1];
        }
        int b0 = c / S2, s0 = c - b0 * S2;
        M[((size_t)(b0 * CCH + r)) * S2P + s0] = a0;
        if (has1) {
            int bs1 = c + 128;
            int b1 = bs1 / S2, s1 = bs1 - b1 * S2;
            M[((size_t)(b1 * CCH + r)) * S2P + s1] = a1;
        }
        if (c >= 68 && c < 80) {
            int rem = c - 68;
            int bb = rem / 3, sp = 49 + rem % 3;
            M[((size_t)(bb * CCH + r)) * S2P + sp] = 0.f;
        }
    }
    grid.sync();

    // ================= stage 3: attn (16 px/tile, 784 tiles) =================
    {
        float* xs  = sh;                 // [96][20]
        float* Ms  = sh + 96 * XSP;      // [96][52]
        float* red = sh;                 // [4][16][52] aliases xs|Ms head
        float* sc  = sh + 6912;          // [16][52]
        float* wl  = sh + 7744;          // [25][52]
        // Wwd staged once (tile-invariant)
#pragma unroll
        for (int k = 0; k < 5; k++) {
            int i = t + 256 * k;
            int j = i / S2P, ss = i - j * S2P;
            wl[i] = (ss < S2) ? Wwd[j * S2 + ss] : 0.f;
        }
        if (t < 20) {
            int i = t + 1280;
            int j = i / S2P, ss = i - j * S2P;
            wl[i] = (ss < S2) ? Wwd[j * S2 + ss] : 0.f;
        }
        int pxg = t & 3, sg = (t >> 2) & 3, slice = t >> 4;
        int r0 = t >> 2, cq = t & 3;
        int r1 = (t + 256) >> 2;         // (t+256)&3 == t&3

        for (int tile = bid; tile < 784; tile += G) {
            int b  = tile / 196;
            int n0 = (tile % 196) * 16;
            const float* xb = x + (size_t)b * CCH * HW + n0;
            const float* Mb = M + (size_t)b * CCH * S2P;
            float4 acc4[4][4];
#pragma unroll
            for (int k = 0; k < 4; k++)
#pragma unroll
                for (int j = 0; j < 4; j++) acc4[k][j] = make_float4(0.f, 0.f, 0.f, 0.f);
            float4 px0, px1, pm0, pm1, pm2, pm3, pm4;

#define ATTN_LOAD(c0)                                                          \
    {                                                                          \
        px0 = *(const float4*)&xb[(size_t)((c0) + r0) * HW + 4 * cq];          \
        if (t < 128)                                                           \
            px1 = *(const float4*)&xb[(size_t)((c0) + r1) * HW + 4 * cq];      \
        const float* srcm = Mb + (size_t)(c0) * S2P;                           \
        pm0 = *(const float4*)&srcm[4 * t];                                    \
        pm1 = *(const float4*)&srcm[4 * (t + 256)];                            \
        pm2 = *(const float4*)&srcm[4 * (t + 512)];                            \
        pm3 = *(const float4*)&srcm[4 * (t + 768)];                            \
        if (t < 224) pm4 = *(const float4*)&srcm[4 * (t + 1024)];              \
    }
#define ATTN_WRITE()                                                           \
    {                                                                          \
        *(float4*)&xs[r0 * XSP + 4 * cq] = px0;                                \
        if (t < 128) *(float4*)&xs[r1 * XSP + 4 * cq] = px1;                   \
        *(float4*)&Ms[4 * t] = pm0;                                            \
        *(float4*)&Ms[4 * (t + 256)] = pm1;                                    \
        *(float4*)&Ms[4 * (t + 512)] = pm2;                                    \
        *(float4*)&Ms[4 * (t + 768)] = pm3;                                    \
        if (t < 224) *(float4*)&Ms[4 * (t + 1024)] = pm4;                      \
    }

            ATTN_LOAD(0);
            for (int chn = 0; chn < 4; chn++) {
                ATTN_WRITE();
                __syncthreads();
                if (chn < 3) { ATTN_LOAD((chn + 1) * 96); }
                int rbase = 6 * slice;
#pragma unroll
                for (int m = 0; m < 6; m++) {
                    int r = rbase + m;
                    const float4 xv = *(const float4*)&xs[r * XSP + 4 * pxg];
#pragma unroll
                    for (int k = 0; k < 3; k++) {
                        int g = sg + 4 * k;
                        const float4 mv = *(const float4*)&Ms[r * S2P + 4 * g];
                        acc4[k][0].x += mv.x * xv.x; acc4[k][0].y += mv.x * xv.y;
                        acc4[k][0].z += mv.x * xv.z; acc4[k][0].w += mv.x * xv.w;
                        acc4[k][1].x += mv.y * xv.x; acc4[k][1].y += mv.y * xv.y;
                        acc4[k][1].z += mv.y * xv.z; acc4[k][1].w += mv.y * xv.w;
                        acc4[k][2].x += mv.z * xv.x; acc4[k][2].y += mv.z * xv.y;
                        acc4[k][2].z += mv.z * xv.z; acc4[k][2].w += mv.z * xv.w;
                        acc4[k][3].x += mv.w * xv.x; acc4[k][3].y += mv.w * xv.y;
                        acc4[k][3].z += mv.w * xv.z; acc4[k][3].w += mv.w * xv.w;
                    }
                    if (sg == 0) {
                        const float4 mv = *(const float4*)&Ms[r * S2P + 48];
                        acc4[3][0].x += mv.x * xv.x; acc4[3][0].y += mv.x * xv.y;
                        acc4[3][0].z += mv.x * xv.z; acc4[3][0].w += mv.x * xv.w;
                        acc4[3][1].x += mv.y * xv.x; acc4[3][1].y += mv.y * xv.y;
                        acc4[3][1].z += mv.y * xv.z; acc4[3][1].w += mv.y * xv.w;
                        acc4[3][2].x += mv.z * xv.x; acc4[3][2].y += mv.z * xv.y;
                        acc4[3][2].z += mv.z * xv.z; acc4[3][2].w += mv.z * xv.w;
                        acc4[3][3].x += mv.w * xv.x; acc4[3][3].y += mv.w * xv.y;
                        acc4[3][3].z += mv.w * xv.z; acc4[3][3].w += mv.w * xv.w;
                    }
                }
                __syncthreads();
            }
#undef ATTN_LOAD
#undef ATTN_WRITE

            // in-wave reduce across 4 slice-groups (lane^16, lane^32)
#pragma unroll
            for (int k = 0; k < 4; k++)
#pragma unroll
                for (int j = 0; j < 4; j++) {
                    acc4[k][j].x += __shfl_xor(acc4[k][j].x, 16);
                    acc4[k][j].y += __shfl_xor(acc4[k][j].y, 16);
                    acc4[k][j].z += __shfl_xor(acc4[k][j].z, 16);
                    acc4[k][j].w += __shfl_xor(acc4[k][j].w, 16);
                    acc4[k][j].x += __shfl_xor(acc4[k][j].x, 32);
                    acc4[k][j].y += __shfl_xor(acc4[k][j].y, 32);
                    acc4[k][j].z += __shfl_xor(acc4[k][j].z, 32);
                    acc4[k][j].w += __shfl_xor(acc4[k][j].w, 32);
                }

            // wave partials -> red[wave][16px][52]
            if ((t & 63) < 16) {
                int wv = t >> 6;
                float* rb = red + (size_t)wv * 16 * S2P;
#pragma unroll
                for (int k = 0; k < 4; k++) {
                    int g = sg + 4 * k;
                    if (g < 13) {
                        *(float4*)&rb[(4 * pxg + 0) * S2P + 4 * g] =
                            make_float4(acc4[k][0].x, acc4[k][1].x, acc4[k][2].x, acc4[k][3].x);
                        *(float4*)&rb[(4 * pxg + 1) * S2P + 4 * g] =
                            make_float4(acc4[k][0].y, acc4[k][1].y, acc4[k][2].y, acc4[k][3].y);
                        *(float4*)&rb[(4 * pxg + 2) * S2P + 4 * g] =
                            make_float4(acc4[k][0].z, acc4[k][1].z, acc4[k][2].z, acc4[k][3].z);
                        *(float4*)&rb[(4 * pxg + 3) * S2P + 4 * g] =
                            make_float4(acc4[k][0].w, acc4[k][1].w, acc4[k][2].w, acc4[k][3].w);
                    }
                }
            }
            __syncthreads();

            // final reduce over 4 waves -> sc
            if (t < 208) {
                int px = t / 13, q = t - px * 13;
                float4 ssum = make_float4(0.f, 0.f, 0.f, 0.f);
#pragma unroll
                for (int wv = 0; wv < 4; wv++) {
                    float4 vv = *(float4*)&red[(size_t)(wv * 16 + px) * S2P + 4 * q];
                    ssum.x += vv.x; ssum.y += vv.y; ssum.z += vv.z; ssum.w += vv.w;
                }
                *(float4*)&sc[px * S2P + 4 * q] = ssum;
            }
            __syncthreads();

            // softmax (threads < 128: 8 lanes per pixel)
            if (t < 128) {
                int px = t >> 3, li = t & 7;
                float mx = -3.4e38f;
#pragma unroll
                for (int k = 0; k < 7; k++) { int s = li + 8 * k; if (s < S2) mx = fmaxf(mx, sc[px * S2P + s]); }
                mx = fmaxf(mx, __shfl_xor(mx, 1, 8));
                mx = fmaxf(mx, __shfl_xor(mx, 2, 8));
                mx = fmaxf(mx, __shfl_xor(mx, 4, 8));
                float e[7]; float sum = 0.f;
#pragma unroll
                for (int k = 0; k < 7; k++) {
                    int s = li + 8 * k;
                    if (s < S2) { e[k] = __expf(sc[px * S2P + s] - mx); sum += e[k]; }
                }
                sum += __shfl_xor(sum, 1, 8);
                sum += __shfl_xor(sum, 2, 8);
                sum += __shfl_xor(sum, 4, 8);
                float inv = 1.f / sum;
#pragma unroll
                for (int k = 0; k < 7; k++) {
                    int s = li + 8 * k;
                    if (s < S2) sc[px * S2P + s] = e[k] * inv;
                }
            }
            __syncthreads();

            // dyn[b,j,n0+px] = sum_s wl[j,s]*sc[px,s]   (400 outs: 256 + 144)
            float* dynb = dyn + (size_t)b * K2 * HW + n0;
#pragma unroll
            for (int pass = 0; pass < 2; pass++) {
                int o = t + 256 * pass;
                if (pass == 0 || t < 144) {
                    int j = o >> 4, px = o & 15;
                    float a = 0.f;
#pragma unroll
                    for (int q = 0; q < 13; q++) {
                        float4 wv4 = *(float4*)&wl[j * S2P + 4 * q];
                        float4 pv  = *(float4*)&sc[px * S2P + 4 * q];
                        a += wv4.x * pv.x + wv4.y * pv.y + wv4.z * pv.z + wv4.w * pv.w;
                    }
                    dynb[(size_t)j * HW + px] = a;
                }
            }
            __syncthreads();   // before next tile overwrites xs/Ms/sc
        }
    }
    grid.sync();

    // ================= stage 4: 5x5 dynamic stencil (672 tiles) =================
    for (int vb = bid; vb < 672; vb += G) {
        float (*xt)[12][60] = (float (*)[12][60])sh;
        int stripe = vb % 7;
        int cgrp   = (vb / 7) % 24;
        int b      = vb / (7 * 24);
        int h0 = stripe * 8;
        int c0 = cgrp * 16;
        const float* xb = x + ((size_t)(b * CCH + c0)) * HW;

        if (t < 192) {
            int cc = t / 12, r = t % 12;
            xt[cc][r][0] = 0.f; xt[cc][r][1] = 0.f;
            xt[cc][r][58] = 0.f; xt[cc][r][59] = 0.f;
        }
#pragma unroll
        for (int k = 0; k < 11; k++) {
            int idx = t + 256 * k;
            if (k < 10 || t < 128) {
                int cc  = idx / 168;
                int rem = idx - cc * 168;
                int r   = rem / 14;
                int q   = rem - r * 14;
                int h   = h0 - 2 + r;
                float4 v = make_float4(0.f, 0.f, 0.f, 0.f);
                if ((unsigned)h < (unsigned)HH)
                    v = *(const float4*)&xb[(size_t)cc * HW + h * WWD + 4 * q];
                xt[cc][r][2 + 4 * q + 0] = v.x;
                xt[cc][r][2 + 4 * q + 1] = v.y;
                xt[cc][r][2 + 4 * q + 2] = v.z;
                xt[cc][r][2 + 4 * q + 3] = v.w;
            }
        }

        bool act = t < 224;
        int w = t % 56;
        int u = t / 56;                  // 0..3 -> rows 2u, 2u+1
        int n = (h0 + 2 * u) * WWD + w;
        float dv0[K2], dv1[K2];
        if (act) {
            const float* db = dyn + (size_t)b * K2 * HW + n;
#pragma unroll
            for (int j = 0; j < K2; j++) {
                dv0[j] = db[(size_t)j * HW];
                dv1[j] = db[(size_t)j * HW + WWD];
            }
        }
        __syncthreads();
        if (act) {
            float* ob = out + ((size_t)(b * CCH + c0)) * HW + n;
#pragma unroll
            for (int cc = 0; cc < 16; cc++) {
                float a0 = 0.f, a1 = 0.f;
#pragma unroll
                for (int rr = 0; rr < 6; rr++) {
                    int lr = 2 * u + rr;
                    float v0 = xt[cc][lr][w + 0];
                    float v1 = xt[cc][lr][w + 1];
                    float v2 = xt[cc][lr][w + 2];
                    float v3 = xt[cc][lr][w + 3];
                    float v4 = xt[cc][lr][w + 4];
                    if (rr < 5) {
                        int o5 = rr * 5;
                        a0 += v0 * dv0[o5] + v1 * dv0[o5 + 1] + v2 * dv0[o5 + 2]
                            + v3 * dv0[o5 + 3] + v4 * dv0[o5 + 4];
                    }
                    if (rr >= 1) {
                        int o5 = (rr - 1) * 5;
                        a1 += v0 * dv1[o5] + v1 * dv1[o5 + 1] + v2 * dv1[o5 + 2]
                            + v3 * dv1[o5 + 3] + v4 * dv1[o5 + 4];
                    }
                }
                ob[(size_t)cc * HW] = a0;
                ob[(size_t)cc * HW + WWD] = a1;
            }
        }
        __syncthreads();   // before next tile overwrites xt
    }
}

extern "C" void kernel_launch(void* const* d_in, const int* in_sizes, int n_in,
                              void* d_out, int out_size, void* d_ws, size_t ws_size,
                              hipStream_t stream) {
    const float* x   = (const float*)d_in[0];
    const float* ctx = (const float*)d_in[1];
    const float* Wq  = (const float*)d_in[2];
    const float* Wk  = (const float*)d_in[3];
    const float* Wwd = (const float*)d_in[4];
    float* out = (float*)d_out;
    float* ws  = (float*)d_ws;

    float* GT  = ws;                    // 384*384            = 147456
    float* M   = ws + 147456;           // B*384*52           =  79872
    float* dyn = ws + 147456 + 79872;   // B*25*3136          = 313600
    float* PT  = dyn;                   // 384*196 = 75264, dead before stage 3 writes dyn

    static int maxb = 0;
    if (maxb == 0) {
        hipOccupancyMaxActiveBlocksPerMultiprocessor(
            &maxb, reinterpret_cast<const void*>(mega_k), 256, 0);
        if (maxb < 1) maxb = 1;
    }
    int gridn = maxb * 256;             // guaranteed co-resident
    if (gridn > 912) gridn = 912;       // no more than stage-1's work

    void* args[] = {(void*)&x, (void*)&ctx, (void*)&Wq, (void*)&Wk, (void*)&Wwd,
                    (void*)&GT, (void*)&PT, (void*)&M, (void*)&dyn, (void*)&out};
    hipLaunchCooperativeKernel(reinterpret_cast<const void*>(mega_k),
                               dim3(gridn), dim3(256), args, 0, stream);
}

// Round 11
// 142.709 us; speedup vs baseline: 1.9249x; 1.9249x over previous
//
#include <hip/hip_runtime.h>

#define BB 4
#define CCH 384
#define HH 56
#define WWD 56
#define HW 3136
#define S2 49
#define S2P 52
#define D2 192
#define K2 25
#define NBS 196         // BB*S2
#define PX 32           // pixels per attn block
#define XS2 32          // xs leading dim (floats)

// ---- Kernel 1 (fused): blocks 0..575 -> GTt GEMM; blocks 576..911 -> pool.
// (unchanged from R9)
__global__ __launch_bounds__(256) void gtpool_k(const float* __restrict__ Wa,
                                                const float* __restrict__ Wb,
                                                const float* __restrict__ ctx,
                                                float* __restrict__ GT,
                                                float* __restrict__ PT) {
    __shared__ float sh[6144];           // GEMM: As|Bs (3072+3072). Pool: part[3584]
    int blk = blockIdx.x;
    int t = threadIdx.x;
    if (blk < 576) {
        float* As = sh;
        float* Bs = sh + 3072;
        int bi = blk % 24, bj = blk / 24;
        int tj = t & 15, ti = t >> 4;
#pragma unroll
        for (int k = 0; k < 3; k++) {
            int idx = t + 256 * k;
            int d = idx >> 2, q = idx & 3;
            *(float4*)&As[idx * 4] = *(const float4*)&Wa[(size_t)d * CCH + bi * 16 + 4 * q];
            *(float4*)&Bs[idx * 4] = *(const float4*)&Wb[(size_t)d * CCH + bj * 16 + 4 * q];
        }
        __syncthreads();
        float acc = 0.f;
#pragma unroll 8
        for (int d = 0; d < D2; d++)
            acc += As[d * 16 + ti] * Bs[d * 16 + tj];
        GT[(size_t)(bi * 16 + ti) * CCH + bj * 16 + tj] = acc;
    } else {
        float* part = sh;                // [32][8][14]
        int pb = blk - 576;              // b*84 + sy*12 + cg
        int b  = pb / 84;
        int rem = pb - b * 84;
        int sy = rem / 12;
        int cg = rem - sy * 12;
        int c0 = cg * 32;
        const float* base = ctx + ((size_t)(b * CCH + c0)) * HW + sy * 8 * WWD;
#pragma unroll
        for (int k = 0; k < 14; k++) {
            int g = t + 256 * k;         // [0, 3584)
            int cc = g / 112;
            int r2 = g - cc * 112;
            float4 v = *(const float4*)(base + (size_t)cc * HW + 4 * r2);
            part[g] = (v.x + v.y) + (v.z + v.w);
        }
        __syncthreads();
        if (t < 224) {
            int cc = t / 7, sx = t - cc * 7;
            float sum = 0.f;
#pragma unroll
            for (int r = 0; r < 8; r++) {
                sum += part[cc * 112 + r * 14 + 2 * sx]
                     + part[cc * 112 + r * 14 + 2 * sx + 1];
            }
            int bs = b * S2 + sy * 7 + sx;
            PT[(size_t)(c0 + cc) * NBS + bs] = sum * (1.f / 64.f);
        }
    }
}

// ---- Kernel 2: M[b,t,s] = GT row t . PT[:, bs]. (unchanged from R9) ----
__global__ __launch_bounds__(256) void mv2_k(const float* __restrict__ GTt,
                                             const float* __restrict__ PT,
                                             float* __restrict__ M) {
    int t = threadIdx.x;
    int r = blockIdx.x * 2 + (t >> 7);   // GT row / output channel
    int c = t & 127;                     // bs0 = c; bs1 = c + 128
    bool has1 = (c < NBS - 128);         // c < 68
    int c1 = has1 ? c + 128 : c;
    const float* g = GTt + (size_t)r * CCH;
    float a0 = 0.f, a1 = 0.f;
#pragma unroll 8
    for (int i = 0; i < CCH; i++) {
        float gv = g[i];
        a0 += gv * PT[(size_t)i * NBS + c];
        a1 += gv * PT[(size_t)i * NBS + c1];
    }
    int b0 = c / S2, s0 = c - b0 * S2;
    M[((size_t)(b0 * CCH + r)) * S2P + s0] = a0;
    if (has1) {
        int bs1 = c + 128;
        int b1 = bs1 / S2, s1 = bs1 - b1 * S2;
        M[((size_t)(b1 * CCH + r)) * S2P + s1] = a1;
    }
    if (c >= 68 && c < 80) {
        int rem = c - 68;                // 0..11
        int bb = rem / 3, sp = 49 + rem % 3;
        M[((size_t)(bb * CCH + r)) * S2P + sp] = 0.f;
    }
}

// ---- Kernel 3: 32 px/block, 512 thr, bounds(512,2). (unchanged from R9) ----
__global__ __launch_bounds__(512, 2) void attn_k(const float* __restrict__ x,
                                                 const float* __restrict__ M,
                                                 const float* __restrict__ Wwd,
                                                 float* __restrict__ dyn) {
    __shared__ __align__(16) float smem[96 * XS2 + 96 * S2P];  // xs | Ms ; red aliases
    __shared__ __align__(16) float sc[PX * S2P];
    __shared__ __align__(16) float wl[K2 * S2P];
    float* xs  = smem;               // [96][32]
    float* Ms  = smem + 96 * XS2;    // [96][52]
    float* red = smem;               // [4][32][52] = 26624B alias

    int b  = blockIdx.x / 98;
    int n0 = (blockIdx.x % 98) * PX;
    int t  = threadIdx.x;
    int pxg = t & 7, sg = (t >> 3) & 3, slice = t >> 5;

    float4 acc4[4][4];
#pragma unroll
    for (int k = 0; k < 4; k++)
#pragma unroll
        for (int j = 0; j < 4; j++) acc4[k][j] = make_float4(0.f, 0.f, 0.f, 0.f);

    const float* xb = x + (size_t)b * CCH * HW + n0;
    const float* Mb = M + (size_t)b * CCH * S2P;

    // hoisted Wwd staging (1300 = 2*512 + 276)
#pragma unroll
    for (int k = 0; k < 2; k++) {
        int i = t + 512 * k;
        int j = i / S2P, ss = i - j * S2P;
        wl[i] = (ss < S2) ? Wwd[j * S2 + ss] : 0.f;
    }
    if (t < 276) {
        int i = t + 1024;
        int j = i / S2P, ss = i - j * S2P;
        wl[i] = (ss < S2) ? Wwd[j * S2 + ss] : 0.f;
    }

    int rx0 = t >> 3, qx = t & 7;        // x f4: row rx0, col-group qx (8 f4/row)
    int rx1 = rx0 + 64;                  // idx t+512
    float4 pxa, pxb, pm0, pm1, pm2;

    // x: 768 f4 (512 + 256); Ms: 1248 f4 (512 + 512 + 224)
#define ATTN_LOAD(c0)                                                          \
    {                                                                          \
        pxa = *(const float4*)&xb[(size_t)((c0) + rx0) * HW + 4 * qx];         \
        if (t < 256)                                                           \
            pxb = *(const float4*)&xb[(size_t)((c0) + rx1) * HW + 4 * qx];     \
        const float* srcm = Mb + (size_t)(c0) * S2P;                           \
        pm0 = *(const float4*)&srcm[4 * t];                                    \
        pm1 = *(const float4*)&srcm[4 * (t + 512)];                            \
        if (t < 224) pm2 = *(const float4*)&srcm[4 * (t + 1024)];              \
    }

#define ATTN_WRITE()                                                           \
    {                                                                          \
        *(float4*)&xs[rx0 * XS2 + 4 * qx] = pxa;                               \
        if (t < 256) *(float4*)&xs[rx1 * XS2 + 4 * qx] = pxb;                  \
        *(float4*)&Ms[4 * t] = pm0;                                            \
        *(float4*)&Ms[4 * (t + 512)] = pm1;                                    \
        if (t < 224) *(float4*)&Ms[4 * (t + 1024)] = pm2;                      \
    }

    ATTN_LOAD(0);
    for (int ch = 0; ch < 4; ch++) {
        ATTN_WRITE();
        __syncthreads();
        if (ch < 3) { ATTN_LOAD((ch + 1) * 96); }
        int rbase = 6 * slice;
#pragma unroll
        for (int m = 0; m < 6; m++) {
            int r = rbase + m;
            const float4 xv = *(const float4*)&xs[r * XS2 + 4 * pxg];
#pragma unroll
            for (int k = 0; k < 3; k++) {
                int g = sg + 4 * k;
                const float4 mv = *(const float4*)&Ms[r * S2P + 4 * g];
                acc4[k][0].x += mv.x * xv.x; acc4[k][0].y += mv.x * xv.y;
                acc4[k][0].z += mv.x * xv.z; acc4[k][0].w += mv.x * xv.w;
                acc4[k][1].x += mv.y * xv.x; acc4[k][1].y += mv.y * xv.y;
                acc4[k][1].z += mv.y * xv.z; acc4[k][1].w += mv.y * xv.w;
                acc4[k][2].x += mv.z * xv.x; acc4[k][2].y += mv.z * xv.y;
                acc4[k][2].z += mv.z * xv.z; acc4[k][2].w += mv.z * xv.w;
                acc4[k][3].x += mv.w * xv.x; acc4[k][3].y += mv.w * xv.y;
                acc4[k][3].z += mv.w * xv.z; acc4[k][3].w += mv.w * xv.w;
            }
            if (sg == 0) {
                const float4 mv = *(const float4*)&Ms[r * S2P + 48];
                acc4[3][0].x += mv.x * xv.x; acc4[3][0].y += mv.x * xv.y;
                acc4[3][0].z += mv.x * xv.z; acc4[3][0].w += mv.x * xv.w;
                acc4[3][1].x += mv.y * xv.x; acc4[3][1].y += mv.y * xv.y;
                acc4[3][1].z += mv.y * xv.z; acc4[3][1].w += mv.y * xv.w;
                acc4[3][2].x += mv.z * xv.x; acc4[3][2].y += mv.z * xv.y;
                acc4[3][2].z += mv.z * xv.z; acc4[3][2].w += mv.z * xv.w;
                acc4[3][3].x += mv.w * xv.x; acc4[3][3].y += mv.w * xv.y;
                acc4[3][3].z += mv.w * xv.z; acc4[3][3].w += mv.w * xv.w;
            }
        }
        __syncthreads();
    }

    // combine the two slices within each wave (lanes ^32)
#pragma unroll
    for (int k = 0; k < 4; k++)
#pragma unroll
        for (int j = 0; j < 4; j++) {
            acc4[k][j].x += __shfl_xor(acc4[k][j].x, 32);
            acc4[k][j].y += __shfl_xor(acc4[k][j].y, 32);
            acc4[k][j].z += __shfl_xor(acc4[k][j].z, 32);
            acc4[k][j].w += __shfl_xor(acc4[k][j].w, 32);
        }

    int l = t & 63, wv = t >> 6;         // 8 waves
    // stage A: waves 0-3 write their partial to red[wv]
    if (wv < 4 && l < 32) {
        float* rb = red + (size_t)wv * PX * S2P;
#pragma unroll
        for (int k = 0; k < 4; k++) {
            int g = sg + 4 * k;
            if (g < 13) {
                *(float4*)&rb[(4 * pxg + 0) * S2P + 4 * g] =
                    make_float4(acc4[k][0].x, acc4[k][1].x, acc4[k][2].x, acc4[k][3].x);
                *(float4*)&rb[(4 * pxg + 1) * S2P + 4 * g] =
                    make_float4(acc4[k][0].y, acc4[k][1].y, acc4[k][2].y, acc4[k][3].y);
                *(float4*)&rb[(4 * pxg + 2) * S2P + 4 * g] =
                    make_float4(acc4[k][0].z, acc4[k][1].z, acc4[k][2].z, acc4[k][3].z);
                *(float4*)&rb[(4 * pxg + 3) * S2P + 4 * g] =
                    make_float4(acc4[k][0].w, acc4[k][1].w, acc4[k][2].w, acc4[k][3].w);
            }
        }
    }
    __syncthreads();
    // stage B: waves 4-7 accumulate onto red[wv-4]
    if (wv >= 4 && l < 32) {
        float* rb = red + (size_t)(wv - 4) * PX * S2P;
#pragma unroll
        for (int k = 0; k < 4; k++) {
            int g = sg + 4 * k;
            if (g < 13) {
                float4 o0 = *(float4*)&rb[(4 * pxg + 0) * S2P + 4 * g];
                float4 o1 = *(float4*)&rb[(4 * pxg + 1) * S2P + 4 * g];
                float4 o2 = *(float4*)&rb[(4 * pxg + 2) * S2P + 4 * g];
                float4 o3 = *(float4*)&rb[(4 * pxg + 3) * S2P + 4 * g];
                o0.x += acc4[k][0].x; o0.y += acc4[k][1].x; o0.z += acc4[k][2].x; o0.w += acc4[k][3].x;
                o1.x += acc4[k][0].y; o1.y += acc4[k][1].y; o1.z += acc4[k][2].y; o1.w += acc4[k][3].y;
                o2.x += acc4[k][0].z; o2.y += acc4[k][1].z; o2.z += acc4[k][2].z; o2.w += acc4[k][3].z;
                o3.x += acc4[k][0].w; o3.y += acc4[k][1].w; o3.z += acc4[k][2].w; o3.w += acc4[k][3].w;
                *(float4*)&rb[(4 * pxg + 0) * S2P + 4 * g] = o0;
                *(float4*)&rb[(4 * pxg + 1) * S2P + 4 * g] = o1;
                *(float4*)&rb[(4 * pxg + 2) * S2P + 4 * g] = o2;
                *(float4*)&rb[(4 * pxg + 3) * S2P + 4 * g] = o3;
            }
        }
    }
    __syncthreads();

    // final reduce over the 4 slots -> sc (32 px x 13 quads = 416 threads)
    if (t < 416) {
        int px = t / 13, q = t - px * 13;
        float4 ssum = make_float4(0.f, 0.f, 0.f, 0.f);
#pragma unroll
        for (int w = 0; w < 4; w++) {
            float4 vv = *(float4*)&red[(size_t)(w * PX + px) * S2P + 4 * q];
            ssum.x += vv.x; ssum.y += vv.y; ssum.z += vv.z; ssum.w += vv.w;
        }
        *(float4*)&sc[px * S2P + 4 * q] = ssum;
    }
    __syncthreads();

    // softmax: 256 threads, 8 lanes per pixel, 32 px
    if (t < 256) {
        int px = t >> 3, li = t & 7;
        float mx = -3.4e38f;
#pragma unroll
        for (int k = 0; k < 7; k++) { int s = li + 8 * k; if (s < S2) mx = fmaxf(mx, sc[px * S2P + s]); }
        mx = fmaxf(mx, __shfl_xor(mx, 1, 8));
        mx = fmaxf(mx, __shfl_xor(mx, 2, 8));
        mx = fmaxf(mx, __shfl_xor(mx, 4, 8));
        float e[7]; float sum = 0.f;
#pragma unroll
        for (int k = 0; k < 7; k++) {
            int s = li + 8 * k;
            if (s < S2) { e[k] = __expf(sc[px * S2P + s] - mx); sum += e[k]; }
        }
        sum += __shfl_xor(sum, 1, 8);
        sum += __shfl_xor(sum, 2, 8);
        sum += __shfl_xor(sum, 4, 8);
        float inv = 1.f / sum;
#pragma unroll
        for (int k = 0; k < 7; k++) {
            int s = li + 8 * k;
            if (s < S2) sc[px * S2P + s] = e[k] * inv;
        }
    }
    __syncthreads();

    // dyn[b,j,n0+px] = sum_s wl[j,s]*sc[px,s]   (800 outs: 512 + 288)
    float* dynb = dyn + (size_t)b * K2 * HW + n0;
#pragma unroll
    for (int pass = 0; pass < 2; pass++) {
        int o = t + 512 * pass;
        if (pass == 0 || t < 288) {
            int j = o >> 5, px = o & 31;
            float a = 0.f;
#pragma unroll
            for (int q = 0; q < 13; q++) {
                float4 wv4 = *(float4*)&wl[j * S2P + 4 * q];
                float4 pv  = *(float4*)&sc[px * S2P + 4 * q];
                a += wv4.x * pv.x + wv4.y * pv.y + wv4.z * pv.z + wv4.w * pv.w;
            }
            dynb[(size_t)j * HW + px] = a;
        }
    }
#undef ATTN_LOAD
#undef ATTN_WRITE
}

// ---- Kernel 4 v2: 5x5 dynamic stencil; 8 ch x 8-row stripe; 2 rows/thread.
// 1344 blocks (was 672), LDS 23KB (was 46KB): occupancy 3 -> ~6 blocks/CU.
// Block order cg-fastest: the 48 blocks sharing a dyn stripe are adjacent
// (L2 reuse of the 44.8KB dv read). dv arrays compile-time indexed -> fits 128 VGPR.
__global__ __launch_bounds__(256, 4) void out_k(const float* __restrict__ x,
                                                const float* __restrict__ dyn,
                                                float* __restrict__ out) {
    __shared__ float xt[8][12][60];
    int blk    = blockIdx.x;
    int cg     = blk % 48;
    int stripe = (blk / 48) % 7;
    int b      = blk / 336;
    int h0 = stripe * 8;
    int c0 = cg * 8;
    int t  = threadIdx.x;
    const float* xb = x + ((size_t)(b * CCH + c0)) * HW;

    if (t < 96) {
        int cc = t / 12, r = t % 12;
        xt[cc][r][0] = 0.f; xt[cc][r][1] = 0.f;
        xt[cc][r][58] = 0.f; xt[cc][r][59] = 0.f;
    }
    // stage 8 ch x 12 rows x 14 f4 = 1344 f4 = 5*256 + 64
#pragma unroll
    for (int k = 0; k < 6; k++) {
        int idx = t + 256 * k;
        if (k < 5 || t < 64) {
            int cc  = idx / 168;
            int rem = idx - cc * 168;
            int r   = rem / 14;
            int q   = rem - r * 14;
            int h   = h0 - 2 + r;
            float4 v = make_float4(0.f, 0.f, 0.f, 0.f);
            if ((unsigned)h < (unsigned)HH)
                v = *(const float4*)&xb[(size_t)cc * HW + h * WWD + 4 * q];
            xt[cc][r][2 + 4 * q + 0] = v.x;
            xt[cc][r][2 + 4 * q + 1] = v.y;
            xt[cc][r][2 + 4 * q + 2] = v.z;
            xt[cc][r][2 + 4 * q + 3] = v.w;
        }
    }

    bool act = t < 224;
    int w = t % 56;
    int u = t / 56;                  // 0..3 -> rows 2u, 2u+1
    int n = (h0 + 2 * u) * WWD + w;
    float dv0[K2], dv1[K2];
    if (act) {
        const float* db = dyn + (size_t)b * K2 * HW + n;
#pragma unroll
        for (int j = 0; j < K2; j++) {
            dv0[j] = db[(size_t)j * HW];
            dv1[j] = db[(size_t)j * HW + WWD];
        }
    }
    __syncthreads();
    if (!act) return;

    float* ob = out + ((size_t)(b * CCH + c0)) * HW + n;
#pragma unroll
    for (int cc = 0; cc < 8; cc++) {
        float a0 = 0.f, a1 = 0.f;
#pragma unroll
        for (int rr = 0; rr < 6; rr++) {
            int lr = 2 * u + rr;
            float v0 = xt[cc][lr][w + 0];
            float v1 = xt[cc][lr][w + 1];
            float v2 = xt[cc][lr][w + 2];
            float v3 = xt[cc][lr][w + 3];
            float v4 = xt[cc][lr][w + 4];
            if (rr < 5) {
                int o5 = rr * 5;
                a0 += v0 * dv0[o5] + v1 * dv0[o5 + 1] + v2 * dv0[o5 + 2]
                    + v3 * dv0[o5 + 3] + v4 * dv0[o5 + 4];
            }
            if (rr >= 1) {
                int o5 = (rr - 1) * 5;
                a1 += v0 * dv1[o5] + v1 * dv1[o5 + 1] + v2 * dv1[o5 + 2]
                    + v3 * dv1[o5 + 3] + v4 * dv1[o5 + 4];
            }
        }
        ob[(size_t)cc * HW] = a0;
        ob[(size_t)cc * HW + WWD] = a1;
    }
}

extern "C" void kernel_launch(void* const* d_in, const int* in_sizes, int n_in,
                              void* d_out, int out_size, void* d_ws, size_t ws_size,
                              hipStream_t stream) {
    const float* x   = (const float*)d_in[0];
    const float* ctx = (const float*)d_in[1];
    const float* Wq  = (const float*)d_in[2];
    const float* Wk  = (const float*)d_in[3];
    const float* Wwd = (const float*)d_in[4];
    float* out = (float*)d_out;
    float* ws  = (float*)d_ws;

    float* GT  = ws;                    // 384*384            = 147456  (GT transposed)
    float* M   = ws + 147456;           // B*384*52           =  79872
    float* dyn = ws + 147456 + 79872;   // B*25*3136          = 313600
    float* PT  = dyn;                   // 384*196 = 75264, dead before attn_k writes dyn

    gtpool_k<<<576 + 336, 256, 0, stream>>>(Wq, Wk, ctx, GT, PT);
    mv2_k<<<CCH / 2, 256, 0, stream>>>(GT, PT, M);
    attn_k<<<BB * 98, 512, 0, stream>>>(x, M, Wwd, dyn);
    out_k<<<BB * 48 * 7, 256, 0, stream>>>(x, dyn, out);
}

// Round 13
// 135.600 us; speedup vs baseline: 2.0258x; 1.0524x over previous
//
#include <hip/hip_runtime.h>

#define BB 4
#define CCH 384
#define HH 56
#define WWD 56
#define HW 3136
#define S2 49
#define S2P 52
#define D2 192
#define K2 25
#define NBS 196         // BB*S2
#define PX 32           // pixels per attn block
#define XS2 32          // xs leading dim (floats)

// ---- Kernel 1 (fused): blocks 0..335 -> pool (heavy, dispatched first);
// blocks 336..911 -> GTt GEMM (cheap tail).
__global__ __launch_bounds__(256) void gtpool_k(const float* __restrict__ Wa,
                                                const float* __restrict__ Wb,
                                                const float* __restrict__ ctx,
                                                float* __restrict__ GT,
                                                float* __restrict__ PT) {
    __shared__ float sh[6144];           // GEMM: As|Bs (3072+3072). Pool: part[3584]
    int blk = blockIdx.x;
    int t = threadIdx.x;
    if (blk >= 336) {
        int g = blk - 336;
        float* As = sh;
        float* Bs = sh + 3072;
        int bi = g % 24, bj = g / 24;
        int tj = t & 15, ti = t >> 4;
#pragma unroll
        for (int k = 0; k < 3; k++) {
            int idx = t + 256 * k;
            int d = idx >> 2, q = idx & 3;
            *(float4*)&As[idx * 4] = *(const float4*)&Wa[(size_t)d * CCH + bi * 16 + 4 * q];
            *(float4*)&Bs[idx * 4] = *(const float4*)&Wb[(size_t)d * CCH + bj * 16 + 4 * q];
        }
        __syncthreads();
        float acc = 0.f;
#pragma unroll 8
        for (int d = 0; d < D2; d++)
            acc += As[d * 16 + ti] * Bs[d * 16 + tj];
        GT[(size_t)(bi * 16 + ti) * CCH + bj * 16 + tj] = acc;
    } else {
        float* part = sh;                // [32][8][14]
        int pb = blk;                    // b*84 + sy*12 + cg
        int b  = pb / 84;
        int rem = pb - b * 84;
        int sy = rem / 12;
        int cg = rem - sy * 12;
        int c0 = cg * 32;
        const float* base = ctx + ((size_t)(b * CCH + c0)) * HW + sy * 8 * WWD;
#pragma unroll
        for (int k = 0; k < 14; k++) {
            int g = t + 256 * k;         // [0, 3584)
            int cc = g / 112;
            int r2 = g - cc * 112;
            float4 v = *(const float4*)(base + (size_t)cc * HW + 4 * r2);
            part[g] = (v.x + v.y) + (v.z + v.w);
        }
        __syncthreads();
        if (t < 224) {
            int cc = t / 7, sx = t - cc * 7;
            float sum = 0.f;
#pragma unroll
            for (int r = 0; r < 8; r++) {
                sum += part[cc * 112 + r * 14 + 2 * sx]
                     + part[cc * 112 + r * 14 + 2 * sx + 1];
            }
            int bs = b * S2 + sy * 7 + sx;
            PT[(size_t)(c0 + cc) * NBS + bs] = sum * (1.f / 64.f);
        }
    }
}

// ---- Kernel 2 v3: one GT row per block (384 blocks, 2x TLP vs 192).
// GT row load is wave-uniform (scalar broadcast); PT reads lane-coalesced.
__global__ __launch_bounds__(256) void mv2_k(const float* __restrict__ GTt,
                                             const float* __restrict__ PT,
                                             float* __restrict__ M) {
    int t = threadIdx.x;
    int r = blockIdx.x;                  // GT row / output channel
    const float* g = GTt + (size_t)r * CCH;
    if (t < NBS) {
        float a0 = 0.f, a1 = 0.f, a2 = 0.f, a3 = 0.f;
#pragma unroll 8
        for (int i = 0; i < CCH; i += 4) {
            a0 += g[i + 0] * PT[(size_t)(i + 0) * NBS + t];
            a1 += g[i + 1] * PT[(size_t)(i + 1) * NBS + t];
            a2 += g[i + 2] * PT[(size_t)(i + 2) * NBS + t];
            a3 += g[i + 3] * PT[(size_t)(i + 3) * NBS + t];
        }
        int b0 = t / S2, s0 = t - b0 * S2;
        M[((size_t)(b0 * CCH + r)) * S2P + s0] = (a0 + a1) + (a2 + a3);
    } else if (t < 208) {
        int rem = t - 196;               // 0..11
        int bb = rem / 3, sp = 49 + rem % 3;
        M[((size_t)(bb * CCH + r)) * S2P + sp] = 0.f;
    }
}

// ---- Kernel 3: 32 px/block, 512 thr, bounds(512,2). Change vs R11:
// chunk-0 global loads issue FIRST (before Wwd staging) -> cold-start
// latency overlaps the wl stores instead of being exposed.
__global__ __launch_bounds__(512, 2) void attn_k(const float* __restrict__ x,
                                                 const float* __restrict__ M,
                                                 const float* __restrict__ Wwd,
                                                 float* __restrict__ dyn) {
    __shared__ __align__(16) float smem[96 * XS2 + 96 * S2P];  // xs | Ms ; red aliases
    __shared__ __align__(16) float sc[PX * S2P];
    __shared__ __align__(16) float wl[K2 * S2P];
    float* xs  = smem;               // [96][32]
    float* Ms  = smem + 96 * XS2;    // [96][52]
    float* red = smem;               // [4][32][52] = 26624B alias

    int b  = blockIdx.x / 98;
    int n0 = (blockIdx.x % 98) * PX;
    int t  = threadIdx.x;
    int pxg = t & 7, sg = (t >> 3) & 3, slice = t >> 5;

    float4 acc4[4][4];
#pragma unroll
    for (int k = 0; k < 4; k++)
#pragma unroll
        for (int j = 0; j < 4; j++) acc4[k][j] = make_float4(0.f, 0.f, 0.f, 0.f);

    const float* xb = x + (size_t)b * CCH * HW + n0;
    const float* Mb = M + (size_t)b * CCH * S2P;

    int rx0 = t >> 3, qx = t & 7;        // x f4: row rx0, col-group qx (8 f4/row)
    int rx1 = rx0 + 64;                  // idx t+512
    float4 pxa, pxb, pm0, pm1, pm2;

    // x: 768 f4 (512 + 256); Ms: 1248 f4 (512 + 512 + 224)
#define ATTN_LOAD(c0)                                                          \
    {                                                                          \
        pxa = *(const float4*)&xb[(size_t)((c0) + rx0) * HW + 4 * qx];         \
        if (t < 256)                                                           \
            pxb = *(const float4*)&xb[(size_t)((c0) + rx1) * HW + 4 * qx];     \
        const float* srcm = Mb + (size_t)(c0) * S2P;                           \
        pm0 = *(const float4*)&srcm[4 * t];                                    \
        pm1 = *(const float4*)&srcm[4 * (t + 512)];                            \
        if (t < 224) pm2 = *(const float4*)&srcm[4 * (t + 1024)];              \
    }

#define ATTN_WRITE()                                                           \
    {                                                                          \
        *(float4*)&xs[rx0 * XS2 + 4 * qx] = pxa;                               \
        if (t < 256) *(float4*)&xs[rx1 * XS2 + 4 * qx] = pxb;                  \
        *(float4*)&Ms[4 * t] = pm0;                                            \
        *(float4*)&Ms[4 * (t + 512)] = pm1;                                    \
        if (t < 224) *(float4*)&Ms[4 * (t + 1024)] = pm2;                      \
    }

    ATTN_LOAD(0);                        // issue cold loads first

    // hoisted Wwd staging (1300 = 2*512 + 276); hides under chunk-0 latency
#pragma unroll
    for (int k = 0; k < 2; k++) {
        int i = t + 512 * k;
        int j = i / S2P, ss = i - j * S2P;
        wl[i] = (ss < S2) ? Wwd[j * S2 + ss] : 0.f;
    }
    if (t < 276) {
        int i = t + 1024;
        int j = i / S2P, ss = i - j * S2P;
        wl[i] = (ss < S2) ? Wwd[j * S2 + ss] : 0.f;
    }

    for (int ch = 0; ch < 4; ch++) {
        ATTN_WRITE();
        __syncthreads();
        if (ch < 3) { ATTN_LOAD((ch + 1) * 96); }
        int rbase = 6 * slice;
#pragma unroll
        for (int m = 0; m < 6; m++) {
            int r = rbase + m;
            const float4 xv = *(const float4*)&xs[r * XS2 + 4 * pxg];
#pragma unroll
            for (int k = 0; k < 3; k++) {
                int g = sg + 4 * k;
                const float4 mv = *(const float4*)&Ms[r * S2P + 4 * g];
                acc4[k][0].x += mv.x * xv.x; acc4[k][0].y += mv.x * xv.y;
                acc4[k][0].z += mv.x * xv.z; acc4[k][0].w += mv.x * xv.w;
                acc4[k][1].x += mv.y * xv.x; acc4[k][1].y += mv.y * xv.y;
                acc4[k][1].z += mv.y * xv.z; acc4[k][1].w += mv.y * xv.w;
                acc4[k][2].x += mv.z * xv.x; acc4[k][2].y += mv.z * xv.y;
                acc4[k][2].z += mv.z * xv.z; acc4[k][2].w += mv.z * xv.w;
                acc4[k][3].x += mv.w * xv.x; acc4[k][3].y += mv.w * xv.y;
                acc4[k][3].z += mv.w * xv.z; acc4[k][3].w += mv.w * xv.w;
            }
            if (sg == 0) {
                const float4 mv = *(const float4*)&Ms[r * S2P + 48];
                acc4[3][0].x += mv.x * xv.x; acc4[3][0].y += mv.x * xv.y;
                acc4[3][0].z += mv.x * xv.z; acc4[3][0].w += mv.x * xv.w;
                acc4[3][1].x += mv.y * xv.x; acc4[3][1].y += mv.y * xv.y;
                acc4[3][1].z += mv.y * xv.z; acc4[3][1].w += mv.y * xv.w;
                acc4[3][2].x += mv.z * xv.x; acc4[3][2].y += mv.z * xv.y;
                acc4[3][2].z += mv.z * xv.z; acc4[3][2].w += mv.z * xv.w;
                acc4[3][3].x += mv.w * xv.x; acc4[3][3].y += mv.w * xv.y;
                acc4[3][3].z += mv.w * xv.z; acc4[3][3].w += mv.w * xv.w;
            }
        }
        __syncthreads();
    }

    // combine the two slices within each wave (lanes ^32)
#pragma unroll
    for (int k = 0; k < 4; k++)
#pragma unroll
        for (int j = 0; j < 4; j++) {
            acc4[k][j].x += __shfl_xor(acc4[k][j].x, 32);
            acc4[k][j].y += __shfl_xor(acc4[k][j].y, 32);
            acc4[k][j].z += __shfl_xor(acc4[k][j].z, 32);
            acc4[k][j].w += __shfl_xor(acc4[k][j].w, 32);
        }

    int l = t & 63, wv = t >> 6;         // 8 waves
    // stage A: waves 0-3 write their partial to red[wv]
    if (wv < 4 && l < 32) {
        float* rb = red + (size_t)wv * PX * S2P;
#pragma unroll
        for (int k = 0; k < 4; k++) {
            int g = sg + 4 * k;
            if (g < 13) {
                *(float4*)&rb[(4 * pxg + 0) * S2P + 4 * g] =
                    make_float4(acc4[k][0].x, acc4[k][1].x, acc4[k][2].x, acc4[k][3].x);
                *(float4*)&rb[(4 * pxg + 1) * S2P + 4 * g] =
                    make_float4(acc4[k][0].y, acc4[k][1].y, acc4[k][2].y, acc4[k][3].y);
                *(float4*)&rb[(4 * pxg + 2) * S2P + 4 * g] =
                    make_float4(acc4[k][0].z, acc4[k][1].z, acc4[k][2].z, acc4[k][3].z);
                *(float4*)&rb[(4 * pxg + 3) * S2P + 4 * g] =
                    make_float4(acc4[k][0].w, acc4[k][1].w, acc4[k][2].w, acc4[k][3].w);
            }
        }
    }
    __syncthreads();
    // stage B: waves 4-7 accumulate onto red[wv-4]
    if (wv >= 4 && l < 32) {
        float* rb = red + (size_t)(wv - 4) * PX * S2P;
#pragma unroll
        for (int k = 0; k < 4; k++) {
            int g = sg + 4 * k;
            if (g < 13) {
                float4 o0 = *(float4*)&rb[(4 * pxg + 0) * S2P + 4 * g];
                float4 o1 = *(float4*)&rb[(4 * pxg + 1) * S2P + 4 * g];
                float4 o2 = *(float4*)&rb[(4 * pxg + 2) * S2P + 4 * g];
                float4 o3 = *(float4*)&rb[(4 * pxg + 3) * S2P + 4 * g];
                o0.x += acc4[k][0].x; o0.y += acc4[k][1].x; o0.z += acc4[k][2].x; o0.w += acc4[k][3].x;
                o1.x += acc4[k][0].y; o1.y += acc4[k][1].y; o1.z += acc4[k][2].y; o1.w += acc4[k][3].y;
                o2.x += acc4[k][0].z; o2.y += acc4[k][1].z; o2.z += acc4[k][2].z; o2.w += acc4[k][3].z;
                o3.x += acc4[k][0].w; o3.y += acc4[k][1].w; o3.z += acc4[k][2].w; o3.w += acc4[k][3].w;
                *(float4*)&rb[(4 * pxg + 0) * S2P + 4 * g] = o0;
                *(float4*)&rb[(4 * pxg + 1) * S2P + 4 * g] = o1;
                *(float4*)&rb[(4 * pxg + 2) * S2P + 4 * g] = o2;
                *(float4*)&rb[(4 * pxg + 3) * S2P + 4 * g] = o3;
            }
        }
    }
    __syncthreads();

    // final reduce over the 4 slots -> sc (32 px x 13 quads = 416 threads)
    if (t < 416) {
        int px = t / 13, q = t - px * 13;
        float4 ssum = make_float4(0.f, 0.f, 0.f, 0.f);
#pragma unroll
        for (int w = 0; w < 4; w++) {
            float4 vv = *(float4*)&red[(size_t)(w * PX + px) * S2P + 4 * q];
            ssum.x += vv.x; ssum.y += vv.y; ssum.z += vv.z; ssum.w += vv.w;
        }
        *(float4*)&sc[px * S2P + 4 * q] = ssum;
    }
    __syncthreads();

    // softmax: 256 threads, 8 lanes per pixel, 32 px
    if (t < 256) {
        int px = t >> 3, li = t & 7;
        float mx = -3.4e38f;
#pragma unroll
        for (int k = 0; k < 7; k++) { int s = li + 8 * k; if (s < S2) mx = fmaxf(mx, sc[px * S2P + s]); }
        mx = fmaxf(mx, __shfl_xor(mx, 1, 8));
        mx = fmaxf(mx, __shfl_xor(mx, 2, 8));
        mx = fmaxf(mx, __shfl_xor(mx, 4, 8));
        float e[7]; float sum = 0.f;
#pragma unroll
        for (int k = 0; k < 7; k++) {
            int s = li + 8 * k;
            if (s < S2) { e[k] = __expf(sc[px * S2P + s] - mx); sum += e[k]; }
        }
        sum += __shfl_xor(sum, 1, 8);
        sum += __shfl_xor(sum, 2, 8);
        sum += __shfl_xor(sum, 4, 8);
        float inv = 1.f / sum;
#pragma unroll
        for (int k = 0; k < 7; k++) {
            int s = li + 8 * k;
            if (s < S2) sc[px * S2P + s] = e[k] * inv;
        }
    }
    __syncthreads();

    // dyn[b,j,n0+px] = sum_s wl[j,s]*sc[px,s]   (800 outs: 512 + 288)
    float* dynb = dyn + (size_t)b * K2 * HW + n0;
#pragma unroll
    for (int pass = 0; pass < 2; pass++) {
        int o = t + 512 * pass;
        if (pass == 0 || t < 288) {
            int j = o >> 5, px = o & 31;
            float a = 0.f;
#pragma unroll
            for (int q = 0; q < 13; q++) {
                float4 wv4 = *(float4*)&wl[j * S2P + 4 * q];
                float4 pv  = *(float4*)&sc[px * S2P + 4 * q];
                a += wv4.x * pv.x + wv4.y * pv.y + wv4.z * pv.z + wv4.w * pv.w;
            }
            dynb[(size_t)j * HW + px] = a;
        }
    }
#undef ATTN_LOAD
#undef ATTN_WRITE
}

// ---- Kernel 4: 5x5 dynamic stencil; 8 ch x 8-row stripe. Change vs R11:
// __launch_bounds__(256, 5) -> 20 waves/CU (was 16). VGPR cap 102 > ~85 need.
__global__ __launch_bounds__(256, 5) void out_k(const float* __restrict__ x,
                                                const float* __restrict__ dyn,
                                                float* __restrict__ out) {
    __shared__ float xt[8][12][60];
    int blk    = blockIdx.x;
    int cg     = blk % 48;
    int stripe = (blk / 48) % 7;
    int b      = blk / 336;
    int h0 = stripe * 8;
    int c0 = cg * 8;
    int t  = threadIdx.x;
    const float* xb = x + ((size_t)(b * CCH + c0)) * HW;

    if (t < 96) {
        int cc = t / 12, r = t % 12;
        xt[cc][r][0] = 0.f; xt[cc][r][1] = 0.f;
        xt[cc][r][58] = 0.f; xt[cc][r][59] = 0.f;
    }
    // stage 8 ch x 12 rows x 14 f4 = 1344 f4 = 5*256 + 64
#pragma unroll
    for (int k = 0; k < 6; k++) {
        int idx = t + 256 * k;
        if (k < 5 || t < 64) {
            int cc  = idx / 168;
            int rem = idx - cc * 168;
            int r   = rem / 14;
            int q   = rem - r * 14;
            int h   = h0 - 2 + r;
            float4 v = make_float4(0.f, 0.f, 0.f, 0.f);
            if ((unsigned)h < (unsigned)HH)
                v = *(const float4*)&xb[(size_t)cc * HW + h * WWD + 4 * q];
            xt[cc][r][2 + 4 * q + 0] = v.x;
            xt[cc][r][2 + 4 * q + 1] = v.y;
            xt[cc][r][2 + 4 * q + 2] = v.z;
            xt[cc][r][2 + 4 * q + 3] = v.w;
        }
    }

    bool act = t < 224;
    int w = t % 56;
    int u = t / 56;                  // 0..3 -> rows 2u, 2u+1
    int n = (h0 + 2 * u) * WWD + w;
    float dv0[K2], dv1[K2];
    if (act) {
        const float* db = dyn + (size_t)b * K2 * HW + n;
#pragma unroll
        for (int j = 0; j < K2; j++) {
            dv0[j] = db[(size_t)j * HW];
            dv1[j] = db[(size_t)j * HW + WWD];
        }
    }
    __syncthreads();
    if (!act) return;

    float* ob = out + ((size_t)(b * CCH + c0)) * HW + n;
#pragma unroll
    for (int cc = 0; cc < 8; cc++) {
        float a0 = 0.f, a1 = 0.f;
#pragma unroll
        for (int rr = 0; rr < 6; rr++) {
            int lr = 2 * u + rr;
            float v0 = xt[cc][lr][w + 0];
            float v1 = xt[cc][lr][w + 1];
            float v2 = xt[cc][lr][w + 2];
            float v3 = xt[cc][lr][w + 3];
            float v4 = xt[cc][lr][w + 4];
            if (rr < 5) {
                int o5 = rr * 5;
                a0 += v0 * dv0[o5] + v1 * dv0[o5 + 1] + v2 * dv0[o5 + 2]
                    + v3 * dv0[o5 + 3] + v4 * dv0[o5 + 4];
            }
            if (rr >= 1) {
                int o5 = (rr - 1) * 5;
                a1 += v0 * dv1[o5] + v1 * dv1[o5 + 1] + v2 * dv1[o5 + 2]
                    + v3 * dv1[o5 + 3] + v4 * dv1[o5 + 4];
            }
        }
        ob[(size_t)cc * HW] = a0;
        ob[(size_t)cc * HW + WWD] = a1;
    }
}

extern "C" void kernel_launch(void* const* d_in, const int* in_sizes, int n_in,
                              void* d_out, int out_size, void* d_ws, size_t ws_size,
                              hipStream_t stream) {
    const float* x   = (const float*)d_in[0];
    const float* ctx = (const float*)d_in[1];
    const float* Wq  = (const float*)d_in[2];
    const float* Wk  = (const float*)d_in[3];
    const float* Wwd = (const float*)d_in[4];
    float* out = (float*)d_out;
    float* ws  = (float*)d_ws;

    float* GT  = ws;                    // 384*384            = 147456  (GT transposed)
    float* M   = ws + 147456;           // B*384*52           =  79872
    float* dyn = ws + 147456 + 79872;   // B*25*3136          = 313600
    float* PT  = dyn;                   // 384*196 = 75264, dead before attn_k writes dyn

    gtpool_k<<<336 + 576, 256, 0, stream>>>(Wq, Wk, ctx, GT, PT);
    mv2_k<<<CCH, 256, 0, stream>>>(GT, PT, M);
    attn_k<<<BB * 98, 512, 0, stream>>>(x, M, Wwd, dyn);
    out_k<<<BB * 48 * 7, 256, 0, stream>>>(x, dyn, out);
}

// Round 14
// 133.437 us; speedup vs baseline: 2.0587x; 1.0162x over previous
//
#include <hip/hip_runtime.h>

#define BB 4
#define CCH 384
#define HH 56
#define WWD 56
#define HW 3136
#define S2 49
#define S2P 52
#define D2 192
#define K2 25
#define NBS 196         // BB*S2
#define PX 32           // pixels per attn block
#define XS2 32          // xs leading dim (floats)

// ---- Kernel 1 (fused): blocks 0..335 -> pool (heavy, dispatched first);
// blocks 336..479 -> GTt GEMM, 32x32 tiles (was 16x16 x 576 blocks).
// 2x2 micro-tile per thread: half the LDS staging traffic, 4 indep FMA chains.
__global__ __launch_bounds__(256) void gtpool_k(const float* __restrict__ Wa,
                                                const float* __restrict__ Wb,
                                                const float* __restrict__ ctx,
                                                float* __restrict__ GT,
                                                float* __restrict__ PT) {
    __shared__ float sh[12288];          // GEMM: As|Bs (6144+6144). Pool: part[3584]
    int blk = blockIdx.x;
    int t = threadIdx.x;
    if (blk >= 336) {
        int g = blk - 336;               // 0..143 -> 12x12 grid of 32x32 tiles
        float* As = sh;                  // [192][32]
        float* Bs = sh + 6144;           // [192][32]
        int bi = g % 12, bj = g / 12;
        int tr = t >> 4, tc = t & 15;    // rows {tr, tr+16}, cols {tc, tc+16}
        // stage: 192 rows x 8 f4 = 1536 f4 each; 6 per thread
#pragma unroll
        for (int k = 0; k < 6; k++) {
            int idx = t + 256 * k;
            int d = idx >> 3, q = idx & 7;
            *(float4*)&As[d * 32 + 4 * q] = *(const float4*)&Wa[(size_t)d * CCH + bi * 32 + 4 * q];
            *(float4*)&Bs[d * 32 + 4 * q] = *(const float4*)&Wb[(size_t)d * CCH + bj * 32 + 4 * q];
        }
        __syncthreads();
        float acc00 = 0.f, acc01 = 0.f, acc10 = 0.f, acc11 = 0.f;
#pragma unroll 8
        for (int d = 0; d < D2; d++) {
            float a0 = As[d * 32 + tr];
            float a1 = As[d * 32 + tr + 16];
            float b0 = Bs[d * 32 + tc];
            float b1 = Bs[d * 32 + tc + 16];
            acc00 += a0 * b0; acc01 += a0 * b1;
            acc10 += a1 * b0; acc11 += a1 * b1;
        }
        size_t r0 = (size_t)(bi * 32 + tr) * CCH + bj * 32 + tc;
        size_t r1 = (size_t)(bi * 32 + tr + 16) * CCH + bj * 32 + tc;
        GT[r0]      = acc00;
        GT[r0 + 16] = acc01;
        GT[r1]      = acc10;
        GT[r1 + 16] = acc11;
    } else {
        float* part = sh;                // [32][8][14]
        int pb = blk;                    // b*84 + sy*12 + cg
        int b  = pb / 84;
        int rem = pb - b * 84;
        int sy = rem / 12;
        int cg = rem - sy * 12;
        int c0 = cg * 32;
        const float* base = ctx + ((size_t)(b * CCH + c0)) * HW + sy * 8 * WWD;
#pragma unroll
        for (int k = 0; k < 14; k++) {
            int g = t + 256 * k;         // [0, 3584)
            int cc = g / 112;
            int r2 = g - cc * 112;
            float4 v = *(const float4*)(base + (size_t)cc * HW + 4 * r2);
            part[g] = (v.x + v.y) + (v.z + v.w);
        }
        __syncthreads();
        if (t < 224) {
            int cc = t / 7, sx = t - cc * 7;
            float sum = 0.f;
#pragma unroll
            for (int r = 0; r < 8; r++) {
                sum += part[cc * 112 + r * 14 + 2 * sx]
                     + part[cc * 112 + r * 14 + 2 * sx + 1];
            }
            int bs = b * S2 + sy * 7 + sx;
            PT[(size_t)(c0 + cc) * NBS + bs] = sum * (1.f / 64.f);
        }
    }
}

// ---- Kernel 2 v3: one GT row per block (384 blocks). (unchanged from R13) ----
__global__ __launch_bounds__(256) void mv2_k(const float* __restrict__ GTt,
                                             const float* __restrict__ PT,
                                             float* __restrict__ M) {
    int t = threadIdx.x;
    int r = blockIdx.x;                  // GT row / output channel
    const float* g = GTt + (size_t)r * CCH;
    if (t < NBS) {
        float a0 = 0.f, a1 = 0.f, a2 = 0.f, a3 = 0.f;
#pragma unroll 8
        for (int i = 0; i < CCH; i += 4) {
            a0 += g[i + 0] * PT[(size_t)(i + 0) * NBS + t];
            a1 += g[i + 1] * PT[(size_t)(i + 1) * NBS + t];
            a2 += g[i + 2] * PT[(size_t)(i + 2) * NBS + t];
            a3 += g[i + 3] * PT[(size_t)(i + 3) * NBS + t];
        }
        int b0 = t / S2, s0 = t - b0 * S2;
        M[((size_t)(b0 * CCH + r)) * S2P + s0] = (a0 + a1) + (a2 + a3);
    } else if (t < 208) {
        int rem = t - 196;               // 0..11
        int bb = rem / 3, sp = 49 + rem % 3;
        M[((size_t)(bb * CCH + r)) * S2P + sp] = 0.f;
    }
}

// ---- Kernel 3: 32 px/block, 512 thr, bounds(512,2). (unchanged from R13) ----
__global__ __launch_bounds__(512, 2) void attn_k(const float* __restrict__ x,
                                                 const float* __restrict__ M,
                                                 const float* __restrict__ Wwd,
                                                 float* __restrict__ dyn) {
    __shared__ __align__(16) float smem[96 * XS2 + 96 * S2P];  // xs | Ms ; red aliases
    __shared__ __align__(16) float sc[PX * S2P];
    __shared__ __align__(16) float wl[K2 * S2P];
    float* xs  = smem;               // [96][32]
    float* Ms  = smem + 96 * XS2;    // [96][52]
    float* red = smem;               // [4][32][52] = 26624B alias

    int b  = blockIdx.x / 98;
    int n0 = (blockIdx.x % 98) * PX;
    int t  = threadIdx.x;
    int pxg = t & 7, sg = (t >> 3) & 3, slice = t >> 5;

    float4 acc4[4][4];
#pragma unroll
    for (int k = 0; k < 4; k++)
#pragma unroll
        for (int j = 0; j < 4; j++) acc4[k][j] = make_float4(0.f, 0.f, 0.f, 0.f);

    const float* xb = x + (size_t)b * CCH * HW + n0;
    const float* Mb = M + (size_t)b * CCH * S2P;

    int rx0 = t >> 3, qx = t & 7;        // x f4: row rx0, col-group qx (8 f4/row)
    int rx1 = rx0 + 64;                  // idx t+512
    float4 pxa, pxb, pm0, pm1, pm2;

    // x: 768 f4 (512 + 256); Ms: 1248 f4 (512 + 512 + 224)
#define ATTN_LOAD(c0)                                                          \
    {                                                                          \
        pxa = *(const float4*)&xb[(size_t)((c0) + rx0) * HW + 4 * qx];         \
        if (t < 256)                                                           \
            pxb = *(const float4*)&xb[(size_t)((c0) + rx1) * HW + 4 * qx];     \
        const float* srcm = Mb + (size_t)(c0) * S2P;                           \
        pm0 = *(const float4*)&srcm[4 * t];                                    \
        pm1 = *(const float4*)&srcm[4 * (t + 512)];                            \
        if (t < 224) pm2 = *(const float4*)&srcm[4 * (t + 1024)];              \
    }

#define ATTN_WRITE()                                                           \
    {                                                                          \
        *(float4*)&xs[rx0 * XS2 + 4 * qx] = pxa;                               \
        if (t < 256) *(float4*)&xs[rx1 * XS2 + 4 * qx] = pxb;                  \
        *(float4*)&Ms[4 * t] = pm0;                                            \
        *(float4*)&Ms[4 * (t + 512)] = pm1;                                    \
        if (t < 224) *(float4*)&Ms[4 * (t + 1024)] = pm2;                      \
    }

    ATTN_LOAD(0);                        // issue cold loads first

    // hoisted Wwd staging (1300 = 2*512 + 276); hides under chunk-0 latency
#pragma unroll
    for (int k = 0; k < 2; k++) {
        int i = t + 512 * k;
        int j = i / S2P, ss = i - j * S2P;
        wl[i] = (ss < S2) ? Wwd[j * S2 + ss] : 0.f;
    }
    if (t < 276) {
        int i = t + 1024;
        int j = i / S2P, ss = i - j * S2P;
        wl[i] = (ss < S2) ? Wwd[j * S2 + ss] : 0.f;
    }

    for (int ch = 0; ch < 4; ch++) {
        ATTN_WRITE();
        __syncthreads();
        if (ch < 3) { ATTN_LOAD((ch + 1) * 96); }
        int rbase = 6 * slice;
#pragma unroll
        for (int m = 0; m < 6; m++) {
            int r = rbase + m;
            const float4 xv = *(const float4*)&xs[r * XS2 + 4 * pxg];
#pragma unroll
            for (int k = 0; k < 3; k++) {
                int g = sg + 4 * k;
                const float4 mv = *(const float4*)&Ms[r * S2P + 4 * g];
                acc4[k][0].x += mv.x * xv.x; acc4[k][0].y += mv.x * xv.y;
                acc4[k][0].z += mv.x * xv.z; acc4[k][0].w += mv.x * xv.w;
                acc4[k][1].x += mv.y * xv.x; acc4[k][1].y += mv.y * xv.y;
                acc4[k][1].z += mv.y * xv.z; acc4[k][1].w += mv.y * xv.w;
                acc4[k][2].x += mv.z * xv.x; acc4[k][2].y += mv.z * xv.y;
                acc4[k][2].z += mv.z * xv.z; acc4[k][2].w += mv.z * xv.w;
                acc4[k][3].x += mv.w * xv.x; acc4[k][3].y += mv.w * xv.y;
                acc4[k][3].z += mv.w * xv.z; acc4[k][3].w += mv.w * xv.w;
            }
            if (sg == 0) {
                const float4 mv = *(const float4*)&Ms[r * S2P + 48];
                acc4[3][0].x += mv.x * xv.x; acc4[3][0].y += mv.x * xv.y;
                acc4[3][0].z += mv.x * xv.z; acc4[3][0].w += mv.x * xv.w;
                acc4[3][1].x += mv.y * xv.x; acc4[3][1].y += mv.y * xv.y;
                acc4[3][1].z += mv.y * xv.z; acc4[3][1].w += mv.y * xv.w;
                acc4[3][2].x += mv.z * xv.x; acc4[3][2].y += mv.z * xv.y;
                acc4[3][2].z += mv.z * xv.z; acc4[3][2].w += mv.z * xv.w;
                acc4[3][3].x += mv.w * xv.x; acc4[3][3].y += mv.w * xv.y;
                acc4[3][3].z += mv.w * xv.z; acc4[3][3].w += mv.w * xv.w;
            }
        }
        __syncthreads();
    }

    // combine the two slices within each wave (lanes ^32)
#pragma unroll
    for (int k = 0; k < 4; k++)
#pragma unroll
        for (int j = 0; j < 4; j++) {
            acc4[k][j].x += __shfl_xor(acc4[k][j].x, 32);
            acc4[k][j].y += __shfl_xor(acc4[k][j].y, 32);
            acc4[k][j].z += __shfl_xor(acc4[k][j].z, 32);
            acc4[k][j].w += __shfl_xor(acc4[k][j].w, 32);
        }

    int l = t & 63, wv = t >> 6;         // 8 waves
    // stage A: waves 0-3 write their partial to red[wv]
    if (wv < 4 && l < 32) {
        float* rb = red + (size_t)wv * PX * S2P;
#pragma unroll
        for (int k = 0; k < 4; k++) {
            int g = sg + 4 * k;
            if (g < 13) {
                *(float4*)&rb[(4 * pxg + 0) * S2P + 4 * g] =
                    make_float4(acc4[k][0].x, acc4[k][1].x, acc4[k][2].x, acc4[k][3].x);
                *(float4*)&rb[(4 * pxg + 1) * S2P + 4 * g] =
                    make_float4(acc4[k][0].y, acc4[k][1].y, acc4[k][2].y, acc4[k][3].y);
                *(float4*)&rb[(4 * pxg + 2) * S2P + 4 * g] =
                    make_float4(acc4[k][0].z, acc4[k][1].z, acc4[k][2].z, acc4[k][3].z);
                *(float4*)&rb[(4 * pxg + 3) * S2P + 4 * g] =
                    make_float4(acc4[k][0].w, acc4[k][1].w, acc4[k][2].w, acc4[k][3].w);
            }
        }
    }
    __syncthreads();
    // stage B: waves 4-7 accumulate onto red[wv-4]
    if (wv >= 4 && l < 32) {
        float* rb = red + (size_t)(wv - 4) * PX * S2P;
#pragma unroll
        for (int k = 0; k < 4; k++) {
            int g = sg + 4 * k;
            if (g < 13) {
                float4 o0 = *(float4*)&rb[(4 * pxg + 0) * S2P + 4 * g];
                float4 o1 = *(float4*)&rb[(4 * pxg + 1) * S2P + 4 * g];
                float4 o2 = *(float4*)&rb[(4 * pxg + 2) * S2P + 4 * g];
                float4 o3 = *(float4*)&rb[(4 * pxg + 3) * S2P + 4 * g];
                o0.x += acc4[k][0].x; o0.y += acc4[k][1].x; o0.z += acc4[k][2].x; o0.w += acc4[k][3].x;
                o1.x += acc4[k][0].y; o1.y += acc4[k][1].y; o1.z += acc4[k][2].y; o1.w += acc4[k][3].y;
                o2.x += acc4[k][0].z; o2.y += acc4[k][1].z; o2.z += acc4[k][2].z; o2.w += acc4[k][3].z;
                o3.x += acc4[k][0].w; o3.y += acc4[k][1].w; o3.z += acc4[k][2].w; o3.w += acc4[k][3].w;
                *(float4*)&rb[(4 * pxg + 0) * S2P + 4 * g] = o0;
                *(float4*)&rb[(4 * pxg + 1) * S2P + 4 * g] = o1;
                *(float4*)&rb[(4 * pxg + 2) * S2P + 4 * g] = o2;
                *(float4*)&rb[(4 * pxg + 3) * S2P + 4 * g] = o3;
            }
        }
    }
    __syncthreads();

    // final reduce over the 4 slots -> sc (32 px x 13 quads = 416 threads)
    if (t < 416) {
        int px = t / 13, q = t - px * 13;
        float4 ssum = make_float4(0.f, 0.f, 0.f, 0.f);
#pragma unroll
        for (int w = 0; w < 4; w++) {
            float4 vv = *(float4*)&red[(size_t)(w * PX + px) * S2P + 4 * q];
            ssum.x += vv.x; ssum.y += vv.y; ssum.z += vv.z; ssum.w += vv.w;
        }
        *(float4*)&sc[px * S2P + 4 * q] = ssum;
    }
    __syncthreads();

    // softmax: 256 threads, 8 lanes per pixel, 32 px
    if (t < 256) {
        int px = t >> 3, li = t & 7;
        float mx = -3.4e38f;
#pragma unroll
        for (int k = 0; k < 7; k++) { int s = li + 8 * k; if (s < S2) mx = fmaxf(mx, sc[px * S2P + s]); }
        mx = fmaxf(mx, __shfl_xor(mx, 1, 8));
        mx = fmaxf(mx, __shfl_xor(mx, 2, 8));
        mx = fmaxf(mx, __shfl_xor(mx, 4, 8));
        float e[7]; float sum = 0.f;
#pragma unroll
        for (int k = 0; k < 7; k++) {
            int s = li + 8 * k;
            if (s < S2) { e[k] = __expf(sc[px * S2P + s] - mx); sum += e[k]; }
        }
        sum += __shfl_xor(sum, 1, 8);
        sum += __shfl_xor(sum, 2, 8);
        sum += __shfl_xor(sum, 4, 8);
        float inv = 1.f / sum;
#pragma unroll
        for (int k = 0; k < 7; k++) {
            int s = li + 8 * k;
            if (s < S2) sc[px * S2P + s] = e[k] * inv;
        }
    }
    __syncthreads();

    // dyn[b,j,n0+px] = sum_s wl[j,s]*sc[px,s]   (800 outs: 512 + 288)
    float* dynb = dyn + (size_t)b * K2 * HW + n0;
#pragma unroll
    for (int pass = 0; pass < 2; pass++) {
        int o = t + 512 * pass;
        if (pass == 0 || t < 288) {
            int j = o >> 5, px = o & 31;
            float a = 0.f;
#pragma unroll
            for (int q = 0; q < 13; q++) {
                float4 wv4 = *(float4*)&wl[j * S2P + 4 * q];
                float4 pv  = *(float4*)&sc[px * S2P + 4 * q];
                a += wv4.x * pv.x + wv4.y * pv.y + wv4.z * pv.z + wv4.w * pv.w;
            }
            dynb[(size_t)j * HW + px] = a;
        }
    }
#undef ATTN_LOAD
#undef ATTN_WRITE
}

// ---- Kernel 4: 5x5 dynamic stencil; 8 ch x 8-row stripe; bounds(256,5).
// (unchanged from R13)
__global__ __launch_bounds__(256, 5) void out_k(const float* __restrict__ x,
                                                const float* __restrict__ dyn,
                                                float* __restrict__ out) {
    __shared__ float xt[8][12][60];
    int blk    = blockIdx.x;
    int cg     = blk % 48;
    int stripe = (blk / 48) % 7;
    int b      = blk / 336;
    int h0 = stripe * 8;
    int c0 = cg * 8;
    int t  = threadIdx.x;
    const float* xb = x + ((size_t)(b * CCH + c0)) * HW;

    if (t < 96) {
        int cc = t / 12, r = t % 12;
        xt[cc][r][0] = 0.f; xt[cc][r][1] = 0.f;
        xt[cc][r][58] = 0.f; xt[cc][r][59] = 0.f;
    }
    // stage 8 ch x 12 rows x 14 f4 = 1344 f4 = 5*256 + 64
#pragma unroll
    for (int k = 0; k < 6; k++) {
        int idx = t + 256 * k;
        if (k < 5 || t < 64) {
            int cc  = idx / 168;
            int rem = idx - cc * 168;
            int r   = rem / 14;
            int q   = rem - r * 14;
            int h   = h0 - 2 + r;
            float4 v = make_float4(0.f, 0.f, 0.f, 0.f);
            if ((unsigned)h < (unsigned)HH)
                v = *(const float4*)&xb[(size_t)cc * HW + h * WWD + 4 * q];
            xt[cc][r][2 + 4 * q + 0] = v.x;
            xt[cc][r][2 + 4 * q + 1] = v.y;
            xt[cc][r][2 + 4 * q + 2] = v.z;
            xt[cc][r][2 + 4 * q + 3] = v.w;
        }
    }

    bool act = t < 224;
    int w = t % 56;
    int u = t / 56;                  // 0..3 -> rows 2u, 2u+1
    int n = (h0 + 2 * u) * WWD + w;
    float dv0[K2], dv1[K2];
    if (act) {
        const float* db = dyn + (size_t)b * K2 * HW + n;
#pragma unroll
        for (int j = 0; j < K2; j++) {
            dv0[j] = db[(size_t)j * HW];
            dv1[j] = db[(size_t)j * HW + WWD];
        }
    }
    __syncthreads();
    if (!act) return;

    float* ob = out + ((size_t)(b * CCH + c0)) * HW + n;
#pragma unroll
    for (int cc = 0; cc < 8; cc++) {
        float a0 = 0.f, a1 = 0.f;
#pragma unroll
        for (int rr = 0; rr < 6; rr++) {
            int lr = 2 * u + rr;
            float v0 = xt[cc][lr][w + 0];
            float v1 = xt[cc][lr][w + 1];
            float v2 = xt[cc][lr][w + 2];
            float v3 = xt[cc][lr][w + 3];
            float v4 = xt[cc][lr][w + 4];
            if (rr < 5) {
                int o5 = rr * 5;
                a0 += v0 * dv0[o5] + v1 * dv0[o5 + 1] + v2 * dv0[o5 + 2]
                    + v3 * dv0[o5 + 3] + v4 * dv0[o5 + 4];
            }
            if (rr >= 1) {
                int o5 = (rr - 1) * 5;
                a1 += v0 * dv1[o5] + v1 * dv1[o5 + 1] + v2 * dv1[o5 + 2]
                    + v3 * dv1[o5 + 3] + v4 * dv1[o5 + 4];
            }
        }
        ob[(size_t)cc * HW] = a0;
        ob[(size_t)cc * HW + WWD] = a1;
    }
}

extern "C" void kernel_launch(void* const* d_in, const int* in_sizes, int n_in,
                              void* d_out, int out_size, void* d_ws, size_t ws_size,
                              hipStream_t stream) {
    const float* x   = (const float*)d_in[0];
    const float* ctx = (const float*)d_in[1];
    const float* Wq  = (const float*)d_in[2];
    const float* Wk  = (const float*)d_in[3];
    const float* Wwd = (const float*)d_in[4];
    float* out = (float*)d_out;
    float* ws  = (float*)d_ws;

    float* GT  = ws;                    // 384*384            = 147456  (GT transposed)
    float* M   = ws + 147456;           // B*384*52           =  79872
    float* dyn = ws + 147456 + 79872;   // B*25*3136          = 313600
    float* PT  = dyn;                   // 384*196 = 75264, dead before attn_k writes dyn

    gtpool_k<<<336 + 144, 256, 0, stream>>>(Wq, Wk, ctx, GT, PT);
    mv2_k<<<CCH, 256, 0, stream>>>(GT, PT, M);
    attn_k<<<BB * 98, 512, 0, stream>>>(x, M, Wwd, dyn);
    out_k<<<BB * 48 * 7, 256, 0, stream>>>(x, dyn, out);
}